// Round 1
// baseline (1140.420 us; speedup 1.0000x reference)
//
#include <hip/hip_runtime.h>
#include <stdint.h>

#define D_MODEL   1024
#define N_EXPERTS 8
#define D_HIDDEN  4096
#define T_TOKENS  8192
#define N_SLOTS   (T_TOKENS * 2)
#define MAX_TILES 136   // sum_e ceil(n_e/128) <= 16384/128 + 7 = 135

typedef __bf16 bf16x8 __attribute__((ext_vector_type(8)));
typedef float  f32x4  __attribute__((ext_vector_type(4)));

__device__ __forceinline__ unsigned short f2bf(float f) {
    unsigned int u = __float_as_uint(f);
    u += 0x7fffu + ((u >> 16) & 1u);   // round-to-nearest-even
    return (unsigned short)(u >> 16);
}

__device__ __forceinline__ void gl_lds16(const void* g, void* l) {
    __builtin_amdgcn_global_load_lds(
        (const __attribute__((address_space(1))) unsigned int*)g,
        (__attribute__((address_space(3))) unsigned int*)l, 16, 0, 0);
}

// ---------------- gating: logits -> top2 -> softmax -> counts ----------------
__global__ __launch_bounds__(256) void gate_kernel(
    const float* __restrict__ x, const float* __restrict__ gw,
    int* __restrict__ route_pack, float* __restrict__ route_w,
    int* __restrict__ cnt)
{
    __shared__ float gws[N_EXPERTS * D_MODEL];
    int tid = threadIdx.x;
    for (int i = tid * 4; i < N_EXPERTS * D_MODEL; i += 256 * 4)
        *(float4*)&gws[i] = *(const float4*)&gw[i];
    __syncthreads();

    int wave = tid >> 6, lane = tid & 63;
    int t = blockIdx.x * 4 + wave;
    const float* xr = x + (size_t)t * D_MODEL;

    float acc[N_EXPERTS];
    for (int e = 0; e < N_EXPERTS; e++) acc[e] = 0.f;
    for (int i = 0; i < 4; i++) {
        float4 xv = *(const float4*)&xr[lane * 4 + i * 256];
        for (int e = 0; e < N_EXPERTS; e++) {
            float4 gv = *(const float4*)&gws[e * D_MODEL + lane * 4 + i * 256];
            acc[e] += xv.x * gv.x + xv.y * gv.y + xv.z * gv.z + xv.w * gv.w;
        }
    }
    for (int e = 0; e < N_EXPERTS; e++)
        for (int off = 32; off >= 1; off >>= 1)
            acc[e] += __shfl_xor(acc[e], off, 64);

    if (lane == 0) {
        int e0 = 0; float v0 = acc[0];
        for (int e = 1; e < N_EXPERTS; e++) if (acc[e] > v0) { v0 = acc[e]; e0 = e; }
        int e1 = (e0 == 0) ? 1 : 0; float v1 = acc[e1];
        for (int e = 0; e < N_EXPERTS; e++)
            if (e != e0 && acc[e] > v1) { v1 = acc[e]; e1 = e; }
        float w0 = 1.f / (1.f + __expf(v1 - v0));
        route_pack[t] = e0 | (e1 << 8);
        route_w[2 * t]     = w0;
        route_w[2 * t + 1] = 1.f - w0;
        atomicAdd(&cnt[e0], 1);
        atomicAdd(&cnt[e1], 1);
    }
}

__global__ void offsets_kernel(const int* __restrict__ cnt,
                               int* __restrict__ off, int* __restrict__ cnt2)
{
    if (threadIdx.x == 0) {
        int a = 0;
        for (int e = 0; e < N_EXPERTS; e++) { off[e] = a; a += cnt[e]; cnt2[e] = 0; }
        off[N_EXPERTS] = a;
    }
}

__global__ __launch_bounds__(256) void scatter_kernel(
    const int* __restrict__ route_pack, const float* __restrict__ route_w,
    const int* __restrict__ off, int* __restrict__ cnt2,
    int* __restrict__ tok_id, float* __restrict__ tok_w)
{
    int t = blockIdx.x * 256 + threadIdx.x;
    if (t >= T_TOKENS) return;
    int p  = route_pack[t];
    int e0 = p & 0xff, e1 = (p >> 8) & 0xff;
    int s0 = off[e0] + atomicAdd(&cnt2[e0], 1);
    tok_id[s0] = t; tok_w[s0] = route_w[2 * t];
    int s1 = off[e1] + atomicAdd(&cnt2[e1], 1);
    tok_id[s1] = t; tok_w[s1] = route_w[2 * t + 1];
}

// ---------------- conversions ----------------
__global__ __launch_bounds__(256) void convert_x_kernel(
    const float* __restrict__ x, unsigned short* __restrict__ xb)
{
    int i = (blockIdx.x * 256 + threadIdx.x) * 4;
    if (i >= T_TOKENS * D_MODEL) return;
    float4 v = *(const float4*)&x[i];
    ushort4 o;
    o.x = f2bf(v.x); o.y = f2bf(v.y); o.z = f2bf(v.z); o.w = f2bf(v.w);
    *(ushort4*)&xb[i] = o;
}

// src: [E][R][C] fp32  ->  dst: [E][C][R] bf16
template <int R, int C>
__global__ __launch_bounds__(256) void transpose_convert_kernel(
    const float* __restrict__ src, unsigned short* __restrict__ dst)
{
    __shared__ float tile[32][33];
    int e = blockIdx.z;
    const float* s = src + (size_t)e * R * C;
    unsigned short* d = dst + (size_t)e * R * C;
    int tx = threadIdx.x, ty = threadIdx.y;     // block (32, 8)
    int c0 = blockIdx.x * 32, r0 = blockIdx.y * 32;
    for (int j = 0; j < 4; j++)
        tile[ty + j * 8][tx] = s[(size_t)(r0 + ty + j * 8) * C + (c0 + tx)];
    __syncthreads();
    for (int j = 0; j < 4; j++)
        d[(size_t)(c0 + ty + j * 8) * R + (r0 + tx)] = f2bf(tile[tx][ty + j * 8]);
}

// ---------------- grouped GEMM1: h = relu(x[tok] @ w1 + b1) ----------------
__global__ __launch_bounds__(256) void gemm1_kernel(
    const unsigned short* __restrict__ xb, const unsigned short* __restrict__ w1t,
    const float* __restrict__ b1, const int* __restrict__ tok_id,
    const int* __restrict__ off, unsigned short* __restrict__ h)
{
    __shared__ unsigned short As[128 * 32];
    __shared__ unsigned short Bs[128 * 32];

    int bx = blockIdx.x;
    int e = -1, slot0 = 0, end = 0;
    {
        int acc = 0;
        for (int i = 0; i < N_EXPERTS; i++) {
            int s = off[i], en = off[i + 1];
            int nt = (en - s + 127) >> 7;
            if (e < 0 && bx < acc + nt) { e = i; slot0 = s + (bx - acc) * 128; end = en; }
            acc += nt;
        }
        if (e < 0) return;
    }
    int n0 = blockIdx.y * 128;
    int tid = threadIdx.x, wave = tid >> 6, lane = tid & 63;
    int lr = lane >> 2, lc = lane & 3;

    f32x4 acc[4][4];
    const f32x4 zero = {0.f, 0.f, 0.f, 0.f};
    for (int i = 0; i < 4; i++) for (int j = 0; j < 4; j++) acc[i][j] = zero;

    int rowA0 = wave * 16 + lr;
    int s0i = min(slot0 + rowA0,      end - 1);
    int s1i = min(slot0 + rowA0 + 64, end - 1);
    const unsigned short* ga0 = xb + (size_t)tok_id[s0i] * D_MODEL + lc * 8;
    const unsigned short* ga1 = xb + (size_t)tok_id[s1i] * D_MODEL + lc * 8;
    const unsigned short* gb0 = w1t + ((size_t)e * D_HIDDEN + n0 + rowA0) * D_MODEL + lc * 8;
    const unsigned short* gb1 = gb0 + (size_t)64 * D_MODEL;
    unsigned short* lA0 = &As[(wave * 16) * 32];
    unsigned short* lA1 = &As[(64 + wave * 16) * 32];
    unsigned short* lB0 = &Bs[(wave * 16) * 32];
    unsigned short* lB1 = &Bs[(64 + wave * 16) * 32];

    int wm = wave & 1, wn = wave >> 1;
    for (int k0 = 0; k0 < D_MODEL; k0 += 32) {
        gl_lds16(ga0 + k0, lA0);
        gl_lds16(ga1 + k0, lA1);
        gl_lds16(gb0 + k0, lB0);
        gl_lds16(gb1 + k0, lB1);
        __syncthreads();
        bf16x8 af[4], bfr[4];
        for (int i = 0; i < 4; i++)
            af[i] = *(const bf16x8*)&As[(wm * 64 + i * 16 + (lane & 15)) * 32 + (lane >> 4) * 8];
        for (int j = 0; j < 4; j++)
            bfr[j] = *(const bf16x8*)&Bs[(wn * 64 + j * 16 + (lane & 15)) * 32 + (lane >> 4) * 8];
        for (int i = 0; i < 4; i++)
            for (int j = 0; j < 4; j++)
                acc[i][j] = __builtin_amdgcn_mfma_f32_16x16x32_bf16(af[i], bfr[j], acc[i][j], 0, 0, 0);
        __syncthreads();
    }

    int quad = lane >> 4, col = lane & 15;
    for (int j = 0; j < 4; j++) {
        int n = n0 + wn * 64 + j * 16 + col;
        float bias = b1[e * D_HIDDEN + n];
        for (int i = 0; i < 4; i++) {
            int rbase = wm * 64 + i * 16 + quad * 4;
            for (int r = 0; r < 4; r++) {
                int slot = slot0 + rbase + r;
                if (slot < end) {
                    float v = acc[i][j][r] + bias;
                    v = v > 0.f ? v : 0.f;
                    h[(size_t)slot * D_HIDDEN + n] = f2bf(v);
                }
            }
        }
    }
}

// ---------------- grouped GEMM2: out[tok] += w * (h @ w2 + b2) ----------------
__global__ __launch_bounds__(256) void gemm2_kernel(
    const unsigned short* __restrict__ h, const unsigned short* __restrict__ w2t,
    const float* __restrict__ b2, const int* __restrict__ tok_id,
    const float* __restrict__ tok_w, const int* __restrict__ off,
    float* __restrict__ out)
{
    __shared__ unsigned short As[128 * 32];
    __shared__ unsigned short Bs[128 * 32];

    int bx = blockIdx.x;
    int e = -1, slot0 = 0, end = 0;
    {
        int acc = 0;
        for (int i = 0; i < N_EXPERTS; i++) {
            int s = off[i], en = off[i + 1];
            int nt = (en - s + 127) >> 7;
            if (e < 0 && bx < acc + nt) { e = i; slot0 = s + (bx - acc) * 128; end = en; }
            acc += nt;
        }
        if (e < 0) return;
    }
    int n0 = blockIdx.y * 128;
    int tid = threadIdx.x, wave = tid >> 6, lane = tid & 63;
    int lr = lane >> 2, lc = lane & 3;

    f32x4 acc[4][4];
    const f32x4 zero = {0.f, 0.f, 0.f, 0.f};
    for (int i = 0; i < 4; i++) for (int j = 0; j < 4; j++) acc[i][j] = zero;

    int rowA0 = wave * 16 + lr;
    int s0i = min(slot0 + rowA0,      end - 1);
    int s1i = min(slot0 + rowA0 + 64, end - 1);
    const unsigned short* ga0 = h + (size_t)s0i * D_HIDDEN + lc * 8;
    const unsigned short* ga1 = h + (size_t)s1i * D_HIDDEN + lc * 8;
    const unsigned short* gb0 = w2t + ((size_t)e * D_MODEL + n0 + rowA0) * D_HIDDEN + lc * 8;
    const unsigned short* gb1 = gb0 + (size_t)64 * D_HIDDEN;
    unsigned short* lA0 = &As[(wave * 16) * 32];
    unsigned short* lA1 = &As[(64 + wave * 16) * 32];
    unsigned short* lB0 = &Bs[(wave * 16) * 32];
    unsigned short* lB1 = &Bs[(64 + wave * 16) * 32];

    int wm = wave & 1, wn = wave >> 1;
    for (int k0 = 0; k0 < D_HIDDEN; k0 += 32) {
        gl_lds16(ga0 + k0, lA0);
        gl_lds16(ga1 + k0, lA1);
        gl_lds16(gb0 + k0, lB0);
        gl_lds16(gb1 + k0, lB1);
        __syncthreads();
        bf16x8 af[4], bfr[4];
        for (int i = 0; i < 4; i++)
            af[i] = *(const bf16x8*)&As[(wm * 64 + i * 16 + (lane & 15)) * 32 + (lane >> 4) * 8];
        for (int j = 0; j < 4; j++)
            bfr[j] = *(const bf16x8*)&Bs[(wn * 64 + j * 16 + (lane & 15)) * 32 + (lane >> 4) * 8];
        for (int i = 0; i < 4; i++)
            for (int j = 0; j < 4; j++)
                acc[i][j] = __builtin_amdgcn_mfma_f32_16x16x32_bf16(af[i], bfr[j], acc[i][j], 0, 0, 0);
        __syncthreads();
    }

    int quad = lane >> 4, col = lane & 15;
    float bias[4];
    for (int j = 0; j < 4; j++)
        bias[j] = b2[e * D_MODEL + n0 + wn * 64 + j * 16 + col];
    for (int i = 0; i < 4; i++) {
        int rbase = wm * 64 + i * 16 + quad * 4;
        for (int r = 0; r < 4; r++) {
            int slot = slot0 + rbase + r;
            if (slot < end) {
                int   tok = tok_id[slot];
                float w   = tok_w[slot];
                float* orow = out + (size_t)tok * D_MODEL;
                for (int j = 0; j < 4; j++) {
                    int n = n0 + wn * 64 + j * 16 + col;
                    atomicAdd(&orow[n], (acc[i][j][r] + bias[j]) * w);
                }
            }
        }
    }
}

// ---------------- launch ----------------
extern "C" void kernel_launch(void* const* d_in, const int* in_sizes, int n_in,
                              void* d_out, int out_size, void* d_ws, size_t ws_size,
                              hipStream_t stream)
{
    const float* x      = (const float*)d_in[0];
    const float* gate_w = (const float*)d_in[1];
    const float* w1     = (const float*)d_in[2];
    const float* b1     = (const float*)d_in[3];
    const float* w2     = (const float*)d_in[4];
    const float* b2     = (const float*)d_in[5];
    float* out = (float*)d_out;

    char* ws = (char*)d_ws;
    size_t o = 0;
    auto alloc = [&](size_t bytes) { void* p = ws + o; o += (bytes + 255) & ~(size_t)255; return p; };
    int*   cnt        = (int*)alloc(32);
    int*   cnt2       = (int*)alloc(32);
    int*   off        = (int*)alloc(64);
    int*   route_pack = (int*)alloc((size_t)T_TOKENS * 4);
    float* route_w    = (float*)alloc((size_t)T_TOKENS * 8);
    int*   tok_id     = (int*)alloc((size_t)N_SLOTS * 4);
    float* tok_w      = (float*)alloc((size_t)N_SLOTS * 4);
    unsigned short* xb  = (unsigned short*)alloc((size_t)T_TOKENS * D_MODEL * 2);
    unsigned short* w1t = (unsigned short*)alloc((size_t)N_EXPERTS * D_MODEL * D_HIDDEN * 2);
    unsigned short* w2t = (unsigned short*)alloc((size_t)N_EXPERTS * D_MODEL * D_HIDDEN * 2);
    unsigned short* h   = (unsigned short*)alloc((size_t)N_SLOTS * D_HIDDEN * 2);

    hipMemsetAsync(cnt, 0, 32, stream);
    hipMemsetAsync(d_out, 0, (size_t)out_size * 4, stream);

    gate_kernel<<<T_TOKENS / 4, 256, 0, stream>>>(x, gate_w, route_pack, route_w, cnt);
    offsets_kernel<<<1, 64, 0, stream>>>(cnt, off, cnt2);
    scatter_kernel<<<T_TOKENS / 256, 256, 0, stream>>>(route_pack, route_w, off, cnt2, tok_id, tok_w);
    convert_x_kernel<<<(T_TOKENS * D_MODEL / 4) / 256, 256, 0, stream>>>(x, xb);
    transpose_convert_kernel<D_MODEL, D_HIDDEN>
        <<<dim3(D_HIDDEN / 32, D_MODEL / 32, N_EXPERTS), dim3(32, 8), 0, stream>>>(w1, w1t);
    transpose_convert_kernel<D_HIDDEN, D_MODEL>
        <<<dim3(D_MODEL / 32, D_HIDDEN / 32, N_EXPERTS), dim3(32, 8), 0, stream>>>(w2, w2t);
    gemm1_kernel<<<dim3(MAX_TILES, D_HIDDEN / 128), 256, 0, stream>>>(xb, w1t, b1, tok_id, off, h);
    gemm2_kernel<<<dim3(MAX_TILES, D_MODEL / 128), 256, 0, stream>>>(h, w2t, b2, tok_id, tok_w, off, out);
}

// Round 2
// 1110.782 us; speedup vs baseline: 1.0267x; 1.0267x over previous
//
#include <hip/hip_runtime.h>
#include <stdint.h>

#define D_MODEL   1024
#define N_EXPERTS 8
#define D_HIDDEN  4096
#define T_TOKENS  8192
#define N_SLOTS   (T_TOKENS * 2)
#define MAX_TILES 136   // sum_e ceil(n_e/128) <= 16384/128 + 7 = 135

typedef __bf16 bf16x8 __attribute__((ext_vector_type(8)));
typedef float  f32x4  __attribute__((ext_vector_type(4)));
typedef unsigned short ushort8 __attribute__((ext_vector_type(8)));

__device__ __forceinline__ unsigned short f2bf(float f) {
    unsigned int u = __float_as_uint(f);
    u += 0x7fffu + ((u >> 16) & 1u);   // round-to-nearest-even
    return (unsigned short)(u >> 16);
}

__device__ __forceinline__ void gl_lds16(const void* g, void* l) {
    __builtin_amdgcn_global_load_lds(
        (const __attribute__((address_space(1))) unsigned int*)g,
        (__attribute__((address_space(3))) unsigned int*)l, 16, 0, 0);
}

// ---------------- gating: logits -> top2 -> softmax -> counts ----------------
__global__ __launch_bounds__(256) void gate_kernel(
    const float* __restrict__ x, const float* __restrict__ gw,
    int* __restrict__ route_pack, float* __restrict__ route_w,
    int* __restrict__ cnt)
{
    __shared__ float gws[N_EXPERTS * D_MODEL];
    int tid = threadIdx.x;
    for (int i = tid * 4; i < N_EXPERTS * D_MODEL; i += 256 * 4)
        *(float4*)&gws[i] = *(const float4*)&gw[i];
    __syncthreads();

    int wave = tid >> 6, lane = tid & 63;
    int t = blockIdx.x * 4 + wave;
    const float* xr = x + (size_t)t * D_MODEL;

    float acc[N_EXPERTS];
    for (int e = 0; e < N_EXPERTS; e++) acc[e] = 0.f;
    for (int i = 0; i < 4; i++) {
        float4 xv = *(const float4*)&xr[lane * 4 + i * 256];
        for (int e = 0; e < N_EXPERTS; e++) {
            float4 gv = *(const float4*)&gws[e * D_MODEL + lane * 4 + i * 256];
            acc[e] += xv.x * gv.x + xv.y * gv.y + xv.z * gv.z + xv.w * gv.w;
        }
    }
    for (int e = 0; e < N_EXPERTS; e++)
        for (int off = 32; off >= 1; off >>= 1)
            acc[e] += __shfl_xor(acc[e], off, 64);

    if (lane == 0) {
        int e0 = 0; float v0 = acc[0];
        for (int e = 1; e < N_EXPERTS; e++) if (acc[e] > v0) { v0 = acc[e]; e0 = e; }
        int e1 = (e0 == 0) ? 1 : 0; float v1 = acc[e1];
        for (int e = 0; e < N_EXPERTS; e++)
            if (e != e0 && acc[e] > v1) { v1 = acc[e]; e1 = e; }
        float w0 = 1.f / (1.f + __expf(v1 - v0));
        route_pack[t] = e0 | (e1 << 8);
        route_w[2 * t]     = w0;
        route_w[2 * t + 1] = 1.f - w0;
        atomicAdd(&cnt[e0], 1);
        atomicAdd(&cnt[e1], 1);
    }
}

__global__ void offsets_kernel(const int* __restrict__ cnt,
                               int* __restrict__ off, int* __restrict__ cnt2)
{
    if (threadIdx.x == 0) {
        int a = 0;
        for (int e = 0; e < N_EXPERTS; e++) { off[e] = a; a += cnt[e]; cnt2[e] = 0; }
        off[N_EXPERTS] = a;
    }
}

__global__ __launch_bounds__(256) void scatter_kernel(
    const int* __restrict__ route_pack, const float* __restrict__ route_w,
    const int* __restrict__ off, int* __restrict__ cnt2,
    int* __restrict__ tok_id, float* __restrict__ tok_w)
{
    int t = blockIdx.x * 256 + threadIdx.x;
    if (t >= T_TOKENS) return;
    int p  = route_pack[t];
    int e0 = p & 0xff, e1 = (p >> 8) & 0xff;
    int s0 = off[e0] + atomicAdd(&cnt2[e0], 1);
    tok_id[s0] = t; tok_w[s0] = route_w[2 * t];
    int s1 = off[e1] + atomicAdd(&cnt2[e1], 1);
    tok_id[s1] = t; tok_w[s1] = route_w[2 * t + 1];
}

// ---------------- conversions ----------------
__global__ __launch_bounds__(256) void convert_x_kernel(
    const float* __restrict__ x, unsigned short* __restrict__ xb)
{
    int i = (blockIdx.x * 256 + threadIdx.x) * 8;
    float4 v0 = *(const float4*)&x[i];
    float4 v1 = *(const float4*)&x[i + 4];
    ushort8 o;
    o[0] = f2bf(v0.x); o[1] = f2bf(v0.y); o[2] = f2bf(v0.z); o[3] = f2bf(v0.w);
    o[4] = f2bf(v1.x); o[5] = f2bf(v1.y); o[6] = f2bf(v1.z); o[7] = f2bf(v1.w);
    *(ushort8*)&xb[i] = o;
}

// src: [E][R][C] fp32  ->  dst: [E][C][R] bf16   (64x64 tiles, 16B-coalesced)
template <int R, int C>
__global__ __launch_bounds__(256) void transpose_convert_kernel(
    const float* __restrict__ src, unsigned short* __restrict__ dst)
{
    __shared__ float tile[64 * 68];
    int e = blockIdx.z;
    const float* s = src + (size_t)e * R * C;
    unsigned short* d = dst + (size_t)e * R * C;
    int r0 = blockIdx.y * 64, c0 = blockIdx.x * 64;
    int t = threadIdx.x;
    {
        int r = t >> 4, c4 = (t & 15) * 4;
        for (int p = 0; p < 4; p++, r += 16)
            *(float4*)&tile[r * 68 + c4] = *(const float4*)&s[(size_t)(r0 + r) * C + c0 + c4];
    }
    __syncthreads();
    {
        int c = t >> 2, rblk = (t & 3) * 8;
        for (int q = 0; q < 2; q++) {
            int rr = q * 32 + rblk;
            ushort8 o;
            for (int j = 0; j < 8; j++) o[j] = f2bf(tile[(rr + j) * 68 + c]);
            *(ushort8*)&d[(size_t)(c0 + c) * R + r0 + rr] = o;
        }
    }
}

// ---------------- grouped GEMM1: h = relu(x[tok] @ w1 + b1) ----------------
__global__ __launch_bounds__(256) void gemm1_kernel(
    const unsigned short* __restrict__ xb, const unsigned short* __restrict__ w1t,
    const float* __restrict__ b1, const int* __restrict__ tok_id,
    const int* __restrict__ off, unsigned short* __restrict__ h)
{
    __shared__ unsigned short smem[64 * 136];   // 17408 B: As(8K)+Bs(8K) / stage(17K)
    unsigned short* As = smem;
    unsigned short* Bs = smem + 128 * 32;
    unsigned short* stage = smem;

    int bx = blockIdx.x;
    int e = -1, slot0 = 0, end = 0;
    {
        int acc = 0;
        for (int i = 0; i < N_EXPERTS; i++) {
            int s = off[i], en = off[i + 1];
            int nt = (en - s + 127) >> 7;
            if (e < 0 && bx < acc + nt) { e = i; slot0 = s + (bx - acc) * 128; end = en; }
            acc += nt;
        }
        if (e < 0) return;
    }
    int n0 = blockIdx.y * 128;
    int tid = threadIdx.x, wave = tid >> 6, lane = tid & 63;
    int lr = lane >> 2, lc = lane & 3;

    f32x4 acc[4][4];
    const f32x4 zero = {0.f, 0.f, 0.f, 0.f};
    for (int i = 0; i < 4; i++) for (int j = 0; j < 4; j++) acc[i][j] = zero;

    int rowA0 = wave * 16 + lr;
    int s0i = min(slot0 + rowA0,      end - 1);
    int s1i = min(slot0 + rowA0 + 64, end - 1);
    const unsigned short* ga0 = xb + (size_t)tok_id[s0i] * D_MODEL + lc * 8;
    const unsigned short* ga1 = xb + (size_t)tok_id[s1i] * D_MODEL + lc * 8;
    const unsigned short* gb0 = w1t + ((size_t)e * D_HIDDEN + n0 + rowA0) * D_MODEL + lc * 8;
    const unsigned short* gb1 = gb0 + (size_t)64 * D_MODEL;
    unsigned short* lA0 = &As[(wave * 16) * 32];
    unsigned short* lA1 = &As[(64 + wave * 16) * 32];
    unsigned short* lB0 = &Bs[(wave * 16) * 32];
    unsigned short* lB1 = &Bs[(64 + wave * 16) * 32];

    int wm = wave & 1, wn = wave >> 1;
    for (int k0 = 0; k0 < D_MODEL; k0 += 32) {
        gl_lds16(ga0 + k0, lA0);
        gl_lds16(ga1 + k0, lA1);
        gl_lds16(gb0 + k0, lB0);
        gl_lds16(gb1 + k0, lB1);
        __syncthreads();
        bf16x8 af[4], bfr[4];
        for (int i = 0; i < 4; i++)
            af[i] = *(const bf16x8*)&As[(wm * 64 + i * 16 + (lane & 15)) * 32 + (lane >> 4) * 8];
        for (int j = 0; j < 4; j++)
            bfr[j] = *(const bf16x8*)&Bs[(wn * 64 + j * 16 + (lane & 15)) * 32 + (lane >> 4) * 8];
        for (int i = 0; i < 4; i++)
            for (int j = 0; j < 4; j++)
                acc[i][j] = __builtin_amdgcn_mfma_f32_16x16x32_bf16(af[i], bfr[j], acc[i][j], 0, 0, 0);
        __syncthreads();
    }

    // epilogue: bias+relu -> bf16 stage in LDS (64x128, stride 136) -> 16B stores
    int quad = lane >> 4, col16 = lane & 15;
    for (int p = 0; p < 2; p++) {
        __syncthreads();
        if (wm == p) {
            for (int j = 0; j < 4; j++) {
                int n = n0 + wn * 64 + j * 16 + col16;
                float bias = b1[e * D_HIDDEN + n];
                for (int i = 0; i < 4; i++)
                    for (int r = 0; r < 4; r++) {
                        float v = acc[i][j][r] + bias;
                        v = v > 0.f ? v : 0.f;
                        stage[(i * 16 + quad * 4 + r) * 136 + wn * 64 + j * 16 + col16] = f2bf(v);
                    }
            }
        }
        __syncthreads();
        int row = tid >> 4, coff = (tid & 15) * 8;
        for (int rr = row; rr < 64; rr += 16) {
            int slot = slot0 + p * 64 + rr;
            if (slot < end)
                *(ushort8*)&h[(size_t)slot * D_HIDDEN + n0 + coff] =
                    *(const ushort8*)&stage[rr * 136 + coff];
        }
    }
}

// ---------------- grouped GEMM2: out[tok] += w * (h @ w2 + b2) ----------------
__global__ __launch_bounds__(256) void gemm2_kernel(
    const unsigned short* __restrict__ h, const unsigned short* __restrict__ w2t,
    const float* __restrict__ b2, const int* __restrict__ tok_id,
    const float* __restrict__ tok_w, const int* __restrict__ off,
    float* __restrict__ out)
{
    __shared__ unsigned short As[128 * 32];
    __shared__ unsigned short Bs[128 * 32];

    int bx = blockIdx.x;
    int e = -1, slot0 = 0, end = 0;
    {
        int acc = 0;
        for (int i = 0; i < N_EXPERTS; i++) {
            int s = off[i], en = off[i + 1];
            int nt = (en - s + 127) >> 7;
            if (e < 0 && bx < acc + nt) { e = i; slot0 = s + (bx - acc) * 128; end = en; }
            acc += nt;
        }
        if (e < 0) return;
    }
    int n0 = blockIdx.y * 128;
    int tid = threadIdx.x, wave = tid >> 6, lane = tid & 63;
    int lr = lane >> 2, lc = lane & 3;

    f32x4 acc[4][4];
    const f32x4 zero = {0.f, 0.f, 0.f, 0.f};
    for (int i = 0; i < 4; i++) for (int j = 0; j < 4; j++) acc[i][j] = zero;

    int rowA0 = wave * 16 + lr;
    int s0i = min(slot0 + rowA0,      end - 1);
    int s1i = min(slot0 + rowA0 + 64, end - 1);
    const unsigned short* ga0 = h + (size_t)s0i * D_HIDDEN + lc * 8;
    const unsigned short* ga1 = h + (size_t)s1i * D_HIDDEN + lc * 8;
    const unsigned short* gb0 = w2t + ((size_t)e * D_MODEL + n0 + rowA0) * D_HIDDEN + lc * 8;
    const unsigned short* gb1 = gb0 + (size_t)64 * D_HIDDEN;
    unsigned short* lA0 = &As[(wave * 16) * 32];
    unsigned short* lA1 = &As[(64 + wave * 16) * 32];
    unsigned short* lB0 = &Bs[(wave * 16) * 32];
    unsigned short* lB1 = &Bs[(64 + wave * 16) * 32];

    int wm = wave & 1, wn = wave >> 1;
    for (int k0 = 0; k0 < D_HIDDEN; k0 += 32) {
        gl_lds16(ga0 + k0, lA0);
        gl_lds16(ga1 + k0, lA1);
        gl_lds16(gb0 + k0, lB0);
        gl_lds16(gb1 + k0, lB1);
        __syncthreads();
        bf16x8 af[4], bfr[4];
        for (int i = 0; i < 4; i++)
            af[i] = *(const bf16x8*)&As[(wm * 64 + i * 16 + (lane & 15)) * 32 + (lane >> 4) * 8];
        for (int j = 0; j < 4; j++)
            bfr[j] = *(const bf16x8*)&Bs[(wn * 64 + j * 16 + (lane & 15)) * 32 + (lane >> 4) * 8];
        for (int i = 0; i < 4; i++)
            for (int j = 0; j < 4; j++)
                acc[i][j] = __builtin_amdgcn_mfma_f32_16x16x32_bf16(af[i], bfr[j], acc[i][j], 0, 0, 0);
        __syncthreads();
    }

    int quad = lane >> 4, col = lane & 15;
    float bias[4];
    for (int j = 0; j < 4; j++)
        bias[j] = b2[e * D_MODEL + n0 + wn * 64 + j * 16 + col];
    for (int i = 0; i < 4; i++) {
        int rbase = wm * 64 + i * 16 + quad * 4;
        for (int r = 0; r < 4; r++) {
            int slot = slot0 + rbase + r;
            if (slot < end) {
                int   tok = tok_id[slot];
                float w   = tok_w[slot];
                float* orow = out + (size_t)tok * D_MODEL;
                for (int j = 0; j < 4; j++) {
                    int n = n0 + wn * 64 + j * 16 + col;
                    atomicAdd(&orow[n], (acc[i][j][r] + bias[j]) * w);
                }
            }
        }
    }
}

// ---------------- launch ----------------
extern "C" void kernel_launch(void* const* d_in, const int* in_sizes, int n_in,
                              void* d_out, int out_size, void* d_ws, size_t ws_size,
                              hipStream_t stream)
{
    const float* x      = (const float*)d_in[0];
    const float* gate_w = (const float*)d_in[1];
    const float* w1     = (const float*)d_in[2];
    const float* b1     = (const float*)d_in[3];
    const float* w2     = (const float*)d_in[4];
    const float* b2     = (const float*)d_in[5];
    float* out = (float*)d_out;

    char* ws = (char*)d_ws;
    size_t o = 0;
    auto alloc = [&](size_t bytes) { void* p = ws + o; o += (bytes + 255) & ~(size_t)255; return p; };
    int*   cnt        = (int*)alloc(32);
    int*   cnt2       = (int*)alloc(32);
    int*   off        = (int*)alloc(64);
    int*   route_pack = (int*)alloc((size_t)T_TOKENS * 4);
    float* route_w    = (float*)alloc((size_t)T_TOKENS * 8);
    int*   tok_id     = (int*)alloc((size_t)N_SLOTS * 4);
    float* tok_w      = (float*)alloc((size_t)N_SLOTS * 4);
    unsigned short* xb  = (unsigned short*)alloc((size_t)T_TOKENS * D_MODEL * 2);
    unsigned short* w1t = (unsigned short*)alloc((size_t)N_EXPERTS * D_MODEL * D_HIDDEN * 2);
    unsigned short* w2t = (unsigned short*)alloc((size_t)N_EXPERTS * D_MODEL * D_HIDDEN * 2);
    unsigned short* h   = (unsigned short*)alloc((size_t)N_SLOTS * D_HIDDEN * 2);

    hipMemsetAsync(cnt, 0, 32, stream);
    hipMemsetAsync(d_out, 0, (size_t)out_size * 4, stream);

    gate_kernel<<<T_TOKENS / 4, 256, 0, stream>>>(x, gate_w, route_pack, route_w, cnt);
    offsets_kernel<<<1, 64, 0, stream>>>(cnt, off, cnt2);
    scatter_kernel<<<T_TOKENS / 256, 256, 0, stream>>>(route_pack, route_w, off, cnt2, tok_id, tok_w);
    convert_x_kernel<<<(T_TOKENS * D_MODEL / 8) / 256, 256, 0, stream>>>(x, xb);
    transpose_convert_kernel<D_MODEL, D_HIDDEN>
        <<<dim3(D_HIDDEN / 64, D_MODEL / 64, N_EXPERTS), dim3(256), 0, stream>>>(w1, w1t);
    transpose_convert_kernel<D_HIDDEN, D_MODEL>
        <<<dim3(D_MODEL / 64, D_HIDDEN / 64, N_EXPERTS), dim3(256), 0, stream>>>(w2, w2t);
    gemm1_kernel<<<dim3(MAX_TILES, D_HIDDEN / 128), 256, 0, stream>>>(xb, w1t, b1, tok_id, off, h);
    gemm2_kernel<<<dim3(MAX_TILES, D_MODEL / 128), 256, 0, stream>>>(h, w2t, b2, tok_id, tok_w, off, out);
}

// Round 3
// 897.923 us; speedup vs baseline: 1.2701x; 1.2371x over previous
//
#include <hip/hip_runtime.h>
#include <stdint.h>

#define D_MODEL   1024
#define N_EXPERTS 8
#define D_HIDDEN  4096
#define T_TOKENS  8192
#define N_SLOTS   (T_TOKENS * 2)
#define MAX_TILES 136   // sum_e ceil(n_e/128) <= 16384/128 + 7 = 135

typedef __bf16 bf16x8 __attribute__((ext_vector_type(8)));
typedef float  f32x4  __attribute__((ext_vector_type(4)));
typedef unsigned short ushort8 __attribute__((ext_vector_type(8)));

__device__ __forceinline__ unsigned short f2bf(float f) {
    unsigned int u = __float_as_uint(f);
    u += 0x7fffu + ((u >> 16) & 1u);   // round-to-nearest-even
    return (unsigned short)(u >> 16);
}
__device__ __forceinline__ float bf2f(unsigned short v) {
    return __uint_as_float((unsigned int)v << 16);
}

__device__ __forceinline__ void gl_lds16(const void* g, void* l) {
    __builtin_amdgcn_global_load_lds(
        (const __attribute__((address_space(1))) unsigned int*)g,
        (__attribute__((address_space(3))) unsigned int*)l, 16, 0, 0);
}

// ------- gating: logits -> top2 -> softmax -> counts; also converts x->bf16 -------
// 512 blocks x 256 thr; 16 tokens/block (4 waves x 4 tokens)
__global__ __launch_bounds__(256) void gate_kernel(
    const float* __restrict__ x, const float* __restrict__ gw,
    unsigned short* __restrict__ xb,
    int* __restrict__ route_pack, float* __restrict__ route_w,
    int* __restrict__ cnt)
{
    __shared__ float gws[N_EXPERTS * D_MODEL];
    __shared__ int hist[N_EXPERTS];
    int tid = threadIdx.x;
    for (int i = tid * 4; i < N_EXPERTS * D_MODEL; i += 256 * 4)
        *(float4*)&gws[i] = *(const float4*)&gw[i];
    if (tid < N_EXPERTS) hist[tid] = 0;
    __syncthreads();

    int wave = tid >> 6, lane = tid & 63;
    for (int tt = 0; tt < 4; tt++) {
        int t = blockIdx.x * 16 + wave * 4 + tt;
        const float* xr = x + (size_t)t * D_MODEL;

        float acc[N_EXPERTS];
        for (int e = 0; e < N_EXPERTS; e++) acc[e] = 0.f;
        for (int i = 0; i < 4; i++) {
            float4 xv = *(const float4*)&xr[lane * 4 + i * 256];
            ushort4 o;
            o.x = f2bf(xv.x); o.y = f2bf(xv.y); o.z = f2bf(xv.z); o.w = f2bf(xv.w);
            *(ushort4*)&xb[(size_t)t * D_MODEL + lane * 4 + i * 256] = o;
            for (int e = 0; e < N_EXPERTS; e++) {
                float4 gv = *(const float4*)&gws[e * D_MODEL + lane * 4 + i * 256];
                acc[e] += xv.x * gv.x + xv.y * gv.y + xv.z * gv.z + xv.w * gv.w;
            }
        }
        for (int e = 0; e < N_EXPERTS; e++)
            for (int off = 32; off >= 1; off >>= 1)
                acc[e] += __shfl_xor(acc[e], off, 64);

        if (lane == 0) {
            int e0 = 0; float v0 = acc[0];
            for (int e = 1; e < N_EXPERTS; e++) if (acc[e] > v0) { v0 = acc[e]; e0 = e; }
            int e1 = (e0 == 0) ? 1 : 0; float v1 = acc[e1];
            for (int e = 0; e < N_EXPERTS; e++)
                if (e != e0 && acc[e] > v1) { v1 = acc[e]; e1 = e; }
            float w0 = 1.f / (1.f + __expf(v1 - v0));
            route_pack[t] = e0 | (e1 << 8);
            route_w[2 * t]     = w0;
            route_w[2 * t + 1] = 1.f - w0;
            atomicAdd(&hist[e0], 1);
            atomicAdd(&hist[e1], 1);
        }
    }
    __syncthreads();
    if (tid < N_EXPERTS) atomicAdd(&cnt[tid], hist[tid]);
}

__global__ void offsets_kernel(const int* __restrict__ cnt,
                               int* __restrict__ off, int* __restrict__ cnt2)
{
    if (threadIdx.x == 0) {
        int a = 0;
        for (int e = 0; e < N_EXPERTS; e++) { off[e] = a; a += cnt[e]; cnt2[e] = 0; }
        off[N_EXPERTS] = a;
    }
}

// ------- scatter via wave ballot-ranking: 1 wave = 64 tokens, 8 atomics/wave -------
__global__ __launch_bounds__(64) void scatter_kernel(
    const int* __restrict__ route_pack, const int* __restrict__ off,
    int* __restrict__ cnt2, int* __restrict__ tok_id, int* __restrict__ inv)
{
    int lane = threadIdx.x;
    int t = blockIdx.x * 64 + lane;
    int p  = route_pack[t];
    int e0 = p & 0xff, e1 = (p >> 8) & 0xff;

    unsigned long long m0[N_EXPERTS], m1[N_EXPERTS];
    for (int e = 0; e < N_EXPERTS; e++) {
        m0[e] = __ballot(e0 == e);
        m1[e] = __ballot(e1 == e);
    }
    int mybase = 0;
    if (lane < N_EXPERTS)
        mybase = atomicAdd(&cnt2[lane], __popcll(m0[lane]) + __popcll(m1[lane]));

    unsigned long long lt = (1ull << lane) - 1ull;
    int b0 = __shfl(mybase, e0);
    int s0 = off[e0] + b0 + (int)__popcll(m0[e0] & lt);
    int b1 = __shfl(mybase, e1);
    int s1 = off[e1] + b1 + (int)__popcll(m0[e1]) + (int)__popcll(m1[e1] & lt);

    tok_id[s0] = t;
    tok_id[s1] = t;
    inv[2 * t]     = s0;
    inv[2 * t + 1] = s1;
}

// src: [E][R][C] fp32  ->  dst: [E][C][R] bf16   (64x64 tiles, 16B-coalesced)
template <int R, int C>
__global__ __launch_bounds__(256) void transpose_convert_kernel(
    const float* __restrict__ src, unsigned short* __restrict__ dst)
{
    __shared__ float tile[64 * 68];
    int e = blockIdx.z;
    const float* s = src + (size_t)e * R * C;
    unsigned short* d = dst + (size_t)e * R * C;
    int r0 = blockIdx.y * 64, c0 = blockIdx.x * 64;
    int t = threadIdx.x;
    {
        int r = t >> 4, c4 = (t & 15) * 4;
        for (int p = 0; p < 4; p++, r += 16)
            *(float4*)&tile[r * 68 + c4] = *(const float4*)&s[(size_t)(r0 + r) * C + c0 + c4];
    }
    __syncthreads();
    {
        int c = t >> 2, rblk = (t & 3) * 8;
        for (int q = 0; q < 2; q++) {
            int rr = q * 32 + rblk;
            ushort8 o;
            for (int j = 0; j < 8; j++) o[j] = f2bf(tile[(rr + j) * 68 + c]);
            *(ushort8*)&d[(size_t)(c0 + c) * R + r0 + rr] = o;
        }
    }
}

// ---------------- grouped GEMM1: h = relu(x[tok] @ w1 + b1) ----------------
__global__ __launch_bounds__(256) void gemm1_kernel(
    const unsigned short* __restrict__ xb, const unsigned short* __restrict__ w1t,
    const float* __restrict__ b1, const int* __restrict__ tok_id,
    const int* __restrict__ off, unsigned short* __restrict__ h)
{
    __shared__ unsigned short smem[64 * 136];   // As(8K)+Bs(8K) / stage(17K)
    unsigned short* As = smem;
    unsigned short* Bs = smem + 128 * 32;
    unsigned short* stage = smem;

    int bx = blockIdx.x;
    int e = -1, slot0 = 0, end = 0;
    {
        int acc = 0;
        for (int i = 0; i < N_EXPERTS; i++) {
            int s = off[i], en = off[i + 1];
            int nt = (en - s + 127) >> 7;
            if (e < 0 && bx < acc + nt) { e = i; slot0 = s + (bx - acc) * 128; end = en; }
            acc += nt;
        }
        if (e < 0) return;
    }
    int n0 = blockIdx.y * 128;
    int tid = threadIdx.x, wave = tid >> 6, lane = tid & 63;
    int lr = lane >> 2, lc = lane & 3;

    f32x4 acc[4][4];
    const f32x4 zero = {0.f, 0.f, 0.f, 0.f};
    for (int i = 0; i < 4; i++) for (int j = 0; j < 4; j++) acc[i][j] = zero;

    int rowA0 = wave * 16 + lr;
    int s0i = min(slot0 + rowA0,      end - 1);
    int s1i = min(slot0 + rowA0 + 64, end - 1);
    const unsigned short* ga0 = xb + (size_t)tok_id[s0i] * D_MODEL + lc * 8;
    const unsigned short* ga1 = xb + (size_t)tok_id[s1i] * D_MODEL + lc * 8;
    const unsigned short* gb0 = w1t + ((size_t)e * D_HIDDEN + n0 + rowA0) * D_MODEL + lc * 8;
    const unsigned short* gb1 = gb0 + (size_t)64 * D_MODEL;
    unsigned short* lA0 = &As[(wave * 16) * 32];
    unsigned short* lA1 = &As[(64 + wave * 16) * 32];
    unsigned short* lB0 = &Bs[(wave * 16) * 32];
    unsigned short* lB1 = &Bs[(64 + wave * 16) * 32];

    int wm = wave & 1, wn = wave >> 1;
    for (int k0 = 0; k0 < D_MODEL; k0 += 32) {
        gl_lds16(ga0 + k0, lA0);
        gl_lds16(ga1 + k0, lA1);
        gl_lds16(gb0 + k0, lB0);
        gl_lds16(gb1 + k0, lB1);
        __syncthreads();
        bf16x8 af[4], bfr[4];
        for (int i = 0; i < 4; i++)
            af[i] = *(const bf16x8*)&As[(wm * 64 + i * 16 + (lane & 15)) * 32 + (lane >> 4) * 8];
        for (int j = 0; j < 4; j++)
            bfr[j] = *(const bf16x8*)&Bs[(wn * 64 + j * 16 + (lane & 15)) * 32 + (lane >> 4) * 8];
        for (int i = 0; i < 4; i++)
            for (int j = 0; j < 4; j++)
                acc[i][j] = __builtin_amdgcn_mfma_f32_16x16x32_bf16(af[i], bfr[j], acc[i][j], 0, 0, 0);
        __syncthreads();
    }

    // epilogue: bias+relu -> bf16 stage in LDS (64x128, stride 136) -> 16B stores
    int quad = lane >> 4, col16 = lane & 15;
    for (int p = 0; p < 2; p++) {
        __syncthreads();
        if (wm == p) {
            for (int j = 0; j < 4; j++) {
                int n = n0 + wn * 64 + j * 16 + col16;
                float bias = b1[e * D_HIDDEN + n];
                for (int i = 0; i < 4; i++)
                    for (int r = 0; r < 4; r++) {
                        float v = acc[i][j][r] + bias;
                        v = v > 0.f ? v : 0.f;
                        stage[(i * 16 + quad * 4 + r) * 136 + wn * 64 + j * 16 + col16] = f2bf(v);
                    }
            }
        }
        __syncthreads();
        int row = tid >> 4, coff = (tid & 15) * 8;
        for (int rr = row; rr < 64; rr += 16) {
            int slot = slot0 + p * 64 + rr;
            if (slot < end)
                *(ushort8*)&h[(size_t)slot * D_HIDDEN + n0 + coff] =
                    *(const ushort8*)&stage[rr * 136 + coff];
        }
    }
}

// -------- grouped GEMM2: y[slot] = h[slot] @ w2 + b2  (bf16, store-only) --------
__global__ __launch_bounds__(256) void gemm2_kernel(
    const unsigned short* __restrict__ h, const unsigned short* __restrict__ w2t,
    const float* __restrict__ b2, const int* __restrict__ off,
    unsigned short* __restrict__ y)
{
    __shared__ unsigned short smem[64 * 136];
    unsigned short* As = smem;
    unsigned short* Bs = smem + 128 * 32;
    unsigned short* stage = smem;

    int bx = blockIdx.x;
    int e = -1, slot0 = 0, end = 0;
    {
        int acc = 0;
        for (int i = 0; i < N_EXPERTS; i++) {
            int s = off[i], en = off[i + 1];
            int nt = (en - s + 127) >> 7;
            if (e < 0 && bx < acc + nt) { e = i; slot0 = s + (bx - acc) * 128; end = en; }
            acc += nt;
        }
        if (e < 0) return;
    }
    int n0 = blockIdx.y * 128;
    int tid = threadIdx.x, wave = tid >> 6, lane = tid & 63;
    int lr = lane >> 2, lc = lane & 3;

    f32x4 acc[4][4];
    const f32x4 zero = {0.f, 0.f, 0.f, 0.f};
    for (int i = 0; i < 4; i++) for (int j = 0; j < 4; j++) acc[i][j] = zero;

    int rowA0 = wave * 16 + lr;
    int s0i = min(slot0 + rowA0,      end - 1);
    int s1i = min(slot0 + rowA0 + 64, end - 1);
    const unsigned short* ga0 = h + (size_t)s0i * D_HIDDEN + lc * 8;
    const unsigned short* ga1 = h + (size_t)s1i * D_HIDDEN + lc * 8;
    const unsigned short* gb0 = w2t + ((size_t)e * D_MODEL + n0 + rowA0) * D_HIDDEN + lc * 8;
    const unsigned short* gb1 = gb0 + (size_t)64 * D_HIDDEN;
    unsigned short* lA0 = &As[(wave * 16) * 32];
    unsigned short* lA1 = &As[(64 + wave * 16) * 32];
    unsigned short* lB0 = &Bs[(wave * 16) * 32];
    unsigned short* lB1 = &Bs[(64 + wave * 16) * 32];

    int wm = wave & 1, wn = wave >> 1;
    for (int k0 = 0; k0 < D_HIDDEN; k0 += 32) {
        gl_lds16(ga0 + k0, lA0);
        gl_lds16(ga1 + k0, lA1);
        gl_lds16(gb0 + k0, lB0);
        gl_lds16(gb1 + k0, lB1);
        __syncthreads();
        bf16x8 af[4], bfr[4];
        for (int i = 0; i < 4; i++)
            af[i] = *(const bf16x8*)&As[(wm * 64 + i * 16 + (lane & 15)) * 32 + (lane >> 4) * 8];
        for (int j = 0; j < 4; j++)
            bfr[j] = *(const bf16x8*)&Bs[(wn * 64 + j * 16 + (lane & 15)) * 32 + (lane >> 4) * 8];
        for (int i = 0; i < 4; i++)
            for (int j = 0; j < 4; j++)
                acc[i][j] = __builtin_amdgcn_mfma_f32_16x16x32_bf16(af[i], bfr[j], acc[i][j], 0, 0, 0);
        __syncthreads();
    }

    // epilogue: +bias -> bf16 stage -> 16B stores into y[slot]
    int quad = lane >> 4, col16 = lane & 15;
    for (int p = 0; p < 2; p++) {
        __syncthreads();
        if (wm == p) {
            for (int j = 0; j < 4; j++) {
                int n = n0 + wn * 64 + j * 16 + col16;
                float bias = b2[e * D_MODEL + n];
                for (int i = 0; i < 4; i++)
                    for (int r = 0; r < 4; r++) {
                        float v = acc[i][j][r] + bias;
                        stage[(i * 16 + quad * 4 + r) * 136 + wn * 64 + j * 16 + col16] = f2bf(v);
                    }
            }
        }
        __syncthreads();
        int row = tid >> 4, coff = (tid & 15) * 8;
        for (int rr = row; rr < 64; rr += 16) {
            int slot = slot0 + p * 64 + rr;
            if (slot < end)
                *(ushort8*)&y[(size_t)slot * D_MODEL + n0 + coff] =
                    *(const ushort8*)&stage[rr * 136 + coff];
        }
    }
}

// -------- combine: out[t] = w0*y[s0] + w1*y[s1] --------
__global__ __launch_bounds__(256) void combine_kernel(
    const unsigned short* __restrict__ y, const int* __restrict__ inv,
    const float* __restrict__ rw, float* __restrict__ out)
{
    int wave = threadIdx.x >> 6, lane = threadIdx.x & 63;
    int t = blockIdx.x * 4 + wave;
    int s0 = inv[2 * t], s1 = inv[2 * t + 1];
    float w0 = rw[2 * t], w1 = rw[2 * t + 1];
    const unsigned short* y0 = y + (size_t)s0 * D_MODEL;
    const unsigned short* y1 = y + (size_t)s1 * D_MODEL;
    float* orow = out + (size_t)t * D_MODEL;
    int c = lane * 16;
    for (int hh = 0; hh < 2; hh++) {
        ushort8 a = *(const ushort8*)&y0[c + hh * 8];
        ushort8 b = *(const ushort8*)&y1[c + hh * 8];
        float4 o0, o1;
        o0.x = w0 * bf2f(a[0]) + w1 * bf2f(b[0]);
        o0.y = w0 * bf2f(a[1]) + w1 * bf2f(b[1]);
        o0.z = w0 * bf2f(a[2]) + w1 * bf2f(b[2]);
        o0.w = w0 * bf2f(a[3]) + w1 * bf2f(b[3]);
        o1.x = w0 * bf2f(a[4]) + w1 * bf2f(b[4]);
        o1.y = w0 * bf2f(a[5]) + w1 * bf2f(b[5]);
        o1.z = w0 * bf2f(a[6]) + w1 * bf2f(b[6]);
        o1.w = w0 * bf2f(a[7]) + w1 * bf2f(b[7]);
        *(float4*)&orow[c + hh * 8]     = o0;
        *(float4*)&orow[c + hh * 8 + 4] = o1;
    }
}

// ---------------- launch ----------------
extern "C" void kernel_launch(void* const* d_in, const int* in_sizes, int n_in,
                              void* d_out, int out_size, void* d_ws, size_t ws_size,
                              hipStream_t stream)
{
    const float* x      = (const float*)d_in[0];
    const float* gate_w = (const float*)d_in[1];
    const float* w1     = (const float*)d_in[2];
    const float* b1     = (const float*)d_in[3];
    const float* w2     = (const float*)d_in[4];
    const float* b2     = (const float*)d_in[5];
    float* out = (float*)d_out;

    char* ws = (char*)d_ws;
    size_t o = 0;
    auto alloc = [&](size_t bytes) { void* p = ws + o; o += (bytes + 255) & ~(size_t)255; return p; };
    int*   cnt        = (int*)alloc(32);
    int*   cnt2       = (int*)alloc(32);
    int*   off        = (int*)alloc(64);
    int*   route_pack = (int*)alloc((size_t)T_TOKENS * 4);
    float* route_w    = (float*)alloc((size_t)T_TOKENS * 8);
    int*   tok_id     = (int*)alloc((size_t)N_SLOTS * 4);
    int*   inv        = (int*)alloc((size_t)T_TOKENS * 8);
    unsigned short* xb  = (unsigned short*)alloc((size_t)T_TOKENS * D_MODEL * 2);
    unsigned short* w1t = (unsigned short*)alloc((size_t)N_EXPERTS * D_MODEL * D_HIDDEN * 2);
    unsigned short* w2t = (unsigned short*)alloc((size_t)N_EXPERTS * D_MODEL * D_HIDDEN * 2);
    unsigned short* h   = (unsigned short*)alloc((size_t)N_SLOTS * D_HIDDEN * 2);
    // y aliases w1t (dead after gemm1): 16384*1024*2 = 33.5 MB <= 67 MB
    unsigned short* y   = w1t;

    hipMemsetAsync(cnt, 0, 32, stream);

    gate_kernel<<<T_TOKENS / 16, 256, 0, stream>>>(x, gate_w, xb, route_pack, route_w, cnt);
    offsets_kernel<<<1, 64, 0, stream>>>(cnt, off, cnt2);
    scatter_kernel<<<T_TOKENS / 64, 64, 0, stream>>>(route_pack, off, cnt2, tok_id, inv);
    transpose_convert_kernel<D_MODEL, D_HIDDEN>
        <<<dim3(D_HIDDEN / 64, D_MODEL / 64, N_EXPERTS), dim3(256), 0, stream>>>(w1, w1t);
    transpose_convert_kernel<D_HIDDEN, D_MODEL>
        <<<dim3(D_MODEL / 64, D_HIDDEN / 64, N_EXPERTS), dim3(256), 0, stream>>>(w2, w2t);
    gemm1_kernel<<<dim3(MAX_TILES, D_HIDDEN / 128), 256, 0, stream>>>(xb, w1t, b1, tok_id, off, h);
    gemm2_kernel<<<dim3(MAX_TILES, D_MODEL / 128), 256, 0, stream>>>(h, w2t, b2, off, y);
    combine_kernel<<<T_TOKENS / 4, 256, 0, stream>>>(y, inv, route_w, out);
}